// Round 8
// baseline (329.426 us; speedup 1.0000x reference)
//
#include <hip/hip_runtime.h>
#include <hip/hip_bf16.h>
#include <math.h>

typedef __bf16 bhalf8 __attribute__((ext_vector_type(8)));
typedef __bf16 bhalf4 __attribute__((ext_vector_type(4)));
typedef float  f32x4  __attribute__((ext_vector_type(4)));

#define MFMA16(a, b, c) __builtin_amdgcn_mfma_f32_16x16x32_bf16(a, b, c, 0, 0, 0)

// ---------------------------------------------------------------------------
// Batched weight transpose+cast: Wt[2560][512] = (wq|wkv|wrel|wo)^T bf16
// ---------------------------------------------------------------------------
__global__ __launch_bounds__(256) void transcast_all(
    const float* __restrict__ Wq, const float* __restrict__ Wkv,
    const float* __restrict__ Wrel, const float* __restrict__ Wo,
    __bf16* __restrict__ Wt)
{
  const int k  = blockIdx.x * 64 + (threadIdx.x & 63);
  const int ng = blockIdx.y * 4 + (threadIdx.x >> 6);
  const float* src; int nn, Ns;
  if (ng < 512)       { src = Wq;   nn = ng;        Ns = 512; }
  else if (ng < 1536) { src = Wkv;  nn = ng - 512;  Ns = 1024; }
  else if (ng < 2048) { src = Wrel; nn = ng - 1536; Ns = 512; }
  else                { src = Wo;   nn = ng - 2048; Ns = 512; }
  Wt[(size_t)ng * 512 + k] = (__bf16)src[(size_t)k * Ns + nn];
}

// ---------------------------------------------------------------------------
// bf16 MFMA GEMM: C[M][N] = A[M][K] @ Bt[N][K]^T
// A_F32: A rows f32 (cast during staging); split handles concat(A0,A1).
// OUT_MODE 0: bf16 C; 1: f32 C; 2: attention-Q epilogue -> qup/qvp
// ---------------------------------------------------------------------------
template <int OUT_MODE, int A_F32>
__global__ __launch_bounds__(256) void gemm_bf16(
    const void* __restrict__ A0v, const void* __restrict__ A1v, int split,
    const __bf16* __restrict__ Bt, void* __restrict__ C, int M, int N, int K,
    const float* __restrict__ pbu, const float* __restrict__ pbv,
    __bf16* __restrict__ qup, __bf16* __restrict__ qvp)
{
  __shared__ __bf16 a_lds[128][40];
  __shared__ __bf16 b_lds[128][40];
  const int m0 = blockIdx.x * 128;
  const int n0 = blockIdx.y * 128;
  const int tid = threadIdx.x;
  const int w = tid >> 6, l = tid & 63;
  const int wn = (w >> 1) * 64, wm = (w & 1) * 64;
  const int li = l & 15, lq = l >> 4;
  const int lk = lq << 3;

  const int srow0 = tid >> 2, srow1 = (tid >> 2) + 64;
  const int skc = (tid & 3) << 3;
  const float* arowf[2];
  const __bf16* arowh[2];
  if (A_F32) {
    const float* A0 = (const float*)A0v;
    const float* A1 = (const float*)A1v;
    const int r0 = m0 + srow0, r1 = m0 + srow1;
    arowf[0] = r0 < split ? A0 + (size_t)r0 * K : A1 + (size_t)(r0 - split) * K;
    arowf[1] = r1 < split ? A0 + (size_t)r1 * K : A1 + (size_t)(r1 - split) * K;
  } else {
    arowh[0] = (const __bf16*)A0v + (size_t)(m0 + srow0) * K;
    arowh[1] = (const __bf16*)A0v + (size_t)(m0 + srow1) * K;
  }

  f32x4 acc[4][4] = {};

  for (int k0 = 0; k0 < K; k0 += 32) {
    __syncthreads();
#pragma unroll
    for (int c = 0; c < 2; ++c) {
      const int row = c ? srow1 : srow0;
      if (A_F32) {
        float4 f0 = *(const float4*)(arowf[c] + k0 + skc);
        float4 f1 = *(const float4*)(arowf[c] + k0 + skc + 4);
        bhalf8 h;
        h[0] = (__bf16)f0.x; h[1] = (__bf16)f0.y; h[2] = (__bf16)f0.z; h[3] = (__bf16)f0.w;
        h[4] = (__bf16)f1.x; h[5] = (__bf16)f1.y; h[6] = (__bf16)f1.z; h[7] = (__bf16)f1.w;
        *(bhalf8*)&a_lds[row][skc] = h;
      } else {
        *(bhalf8*)&a_lds[row][skc] = *(const bhalf8*)(arowh[c] + k0 + skc);
      }
      *(bhalf8*)&b_lds[row][skc] = *(const bhalf8*)(Bt + (size_t)(n0 + row) * K + k0 + skc);
    }
    __syncthreads();
    bhalf8 af[4], bf_[4];
#pragma unroll
    for (int s = 0; s < 4; ++s) {
      af[s]  = *(const bhalf8*)&b_lds[wn + s * 16 + li][lk];
      bf_[s] = *(const bhalf8*)&a_lds[wm + s * 16 + li][lk];
    }
#pragma unroll
    for (int ns = 0; ns < 4; ++ns)
#pragma unroll
      for (int ms = 0; ms < 4; ++ms)
        acc[ns][ms] = MFMA16(af[ns], bf_[ms], acc[ns][ms]);
  }

  const int lr = lq << 2;
#pragma unroll
  for (int ms = 0; ms < 4; ++ms) {
    const int m = m0 + wm + ms * 16 + li;
#pragma unroll
    for (int ns = 0; ns < 4; ++ns) {
      const int n = n0 + wn + ns * 16 + lr;
      if (OUT_MODE == 1) {
        *(f32x4*)((float*)C + (size_t)m * N + n) = acc[ns][ms];
      } else if (OUT_MODE == 0) {
        bhalf4 pk;
#pragma unroll
        for (int r = 0; r < 4; ++r) pk[r] = (__bf16)acc[ns][ms][r];
        *(bhalf4*)((__bf16*)C + (size_t)m * N + n) = pk;
      } else {
        const int i = m >> 2, bb = m & 3, hd = n >> 6;
        float4 u4 = *(const float4*)(pbu + n);
        float4 v4 = *(const float4*)(pbv + n);
        const size_t off = (((size_t)bb * 8 + hd) * 512 + i) * 64 + (n & 63);
        bhalf4 pu, pv;
        pu[0] = (__bf16)((acc[ns][ms][0] + u4.x) * 0.125f);
        pu[1] = (__bf16)((acc[ns][ms][1] + u4.y) * 0.125f);
        pu[2] = (__bf16)((acc[ns][ms][2] + u4.z) * 0.125f);
        pu[3] = (__bf16)((acc[ns][ms][3] + u4.w) * 0.125f);
        pv[0] = (__bf16)((acc[ns][ms][0] + v4.x) * 0.125f);
        pv[1] = (__bf16)((acc[ns][ms][1] + v4.y) * 0.125f);
        pv[2] = (__bf16)((acc[ns][ms][2] + v4.z) * 0.125f);
        pv[3] = (__bf16)((acc[ns][ms][3] + v4.w) * 0.125f);
        *(bhalf4*)(qup + off) = pu;
        *(bhalf4*)(qvp + off) = pv;
      }
    }
  }
}

// ---------------------------------------------------------------------------
// V transpose: vtb[plane][d][t]
// ---------------------------------------------------------------------------
__global__ __launch_bounds__(256) void vtrans(const __bf16* __restrict__ kvb,
                                              __bf16* __restrict__ vtb)
{
  __shared__ __bf16 T2[64][72];
  const int t0 = blockIdx.x * 64;
  const int p = blockIdx.y;
  const int b = p >> 3, n = p & 7;
  const int tid = threadIdx.x;
#pragma unroll
  for (int c = 0; c < 2; ++c) {
    const int e = c * 256 + tid;
    const int tl = e >> 3, d8 = (e & 7) << 3;
    bhalf8 v8 = *(const bhalf8*)(kvb + ((size_t)(t0 + tl) * 4 + b) * 1024 + 512 + n * 64 + d8);
#pragma unroll
    for (int j = 0; j < 8; ++j) T2[d8 + j][tl] = v8[j];
  }
  __syncthreads();
#pragma unroll
  for (int c = 0; c < 2; ++c) {
    const int e = c * 256 + tid;
    const int d = e >> 3, t8 = (e & 7) << 3;
    bhalf8 v = *(const bhalf8*)&T2[d][t8];
    *(bhalf8*)(vtb + ((size_t)p * 64 + d) * 2048 + t0 + t8) = v;
  }
}

// ---------------------------------------------------------------------------
// attn_v5: barrier-free main loop. Grid 512 = (plane, i0-block of 32), 8 waves.
// Wave w: i-subtile it=w&1 (16 rows), t-quarter ts=w>>1 (32 t's per 128-tile).
// Per wave: private 48-row BD window (wave-private LDS), AC via mfma,
// in-register row softmax (intra-wave shfl only), private running (m,l),
// private PV partial O (16i x 64d). One barrier pair at the end merges the
// 4 waves per i-subtile (split-K style). Streams pb (unnormalized P bf16)
// and ms (per-32t-slice max) for am_final.
// ---------------------------------------------------------------------------
__global__ __launch_bounds__(512, 4) void attn_v5(
    const __bf16* __restrict__ qup, const __bf16* __restrict__ qvp,
    const __bf16* __restrict__ kvb, const __bf16* __restrict__ relb,
    const __bf16* __restrict__ vtb, const float* __restrict__ indice,
    __bf16* __restrict__ vecb, float* __restrict__ ml,
    __bf16* __restrict__ pb, float* __restrict__ ms)
{
  // bdw: [8][48][18] f32 = 27648 B ; pw: [8][16][36] bf16 = 9216 B
  // obuf overlay at end: [8][16][68] f32 = 34816 B  (<= 36864)
  __shared__ __align__(16) char smem_raw[36864];
  __shared__ float mlw[8][16][2];
  float*  bdw = (float*)smem_raw;
  __bf16* pw  = (__bf16*)(smem_raw + 27648);
  float*  obuf = (float*)smem_raw;

  const int bid = blockIdx.x;
  const int wrk = ((bid & 7) << 6) | (bid >> 3);
  const int plane = wrk >> 4;
  const int i0 = (wrk & 15) << 5;
  const int b = plane >> 3, n = plane & 7;
  const int tid = threadIdx.x;
  const int w = tid >> 6, l = tid & 63;
  const int li = l & 15, lq = l >> 4;
  const int it = w & 1, ts = w >> 1;
  const int i = i0 + it * 16 + li;          // this lane's query row
  const int base_r = (2 * ts + 1 - it) << 4; // BD window start (tile-local)

  float*  bdww = bdw + w * (48 * 18);
  __bf16* pww  = pw + w * (16 * 36);

  // Q fragments (pre-biased, pre-scaled) + gates for this lane's i
  const __bf16* qp = qup + ((size_t)plane * 512 + i) * 64;
  const __bf16* qq = qvp + ((size_t)plane * 512 + i) * 64;
  bhalf8 qu0 = *(const bhalf8*)(qp + lq * 8);
  bhalf8 qu1 = *(const bhalf8*)(qp + 32 + lq * 8);
  bhalf8 qv0 = *(const bhalf8*)(qq + lq * 8);
  bhalf8 qv1 = *(const bhalf8*)(qq + 32 + lq * 8);
  const float* gp = indice + ((size_t)i * 4 + b) * 4;
  const float g0 = gp[0], g1 = gp[1], g2 = gp[2], g3 = gp[3];

  const __bf16* vbase = vtb + (size_t)plane * 131072;

  float m_run = -1e30f, l_run = 0.f;
  f32x4 oacc[4] = {};
  const int nt = ((1536 + i0 + 31) >> 7) + 1;

  for (int tile = 0; tile < nt; ++tile) {
    const int tb = tile << 7;
    const int wbase = tb + 480 - i0 + base_r;   // global rel row of window row 0

    // ---- BD: 3 private r-subtiles into wave-private bdw ----
#pragma unroll
    for (int rs = 0; rs < 3; ++rs) {
      int grow = wbase + rs * 16 + li;
      grow = grow > 2047 ? 2047 : grow;
      const __bf16* rp = relb + ((size_t)grow * 4 + b) * 512 + n * 64;
      bhalf8 a0 = *(const bhalf8*)(rp + lq * 8);
      bhalf8 a1 = *(const bhalf8*)(rp + 32 + lq * 8);
      f32x4 c = {0.f, 0.f, 0.f, 0.f};
      c = MFMA16(a0, qv0, c);
      c = MFMA16(a1, qv1, c);
#pragma unroll
      for (int r = 0; r < 4; ++r) {
        const int rl = rs * 16 + lq * 4 + r;
        int rk = (wbase + rl) >> 9; rk = rk > 3 ? 3 : rk;
        const float gk = rk == 0 ? g0 : (rk == 1 ? g1 : (rk == 2 ? g2 : g3));
        bdww[rl * 18 + li] = c[r] * gk;
      }
    }
    // ---- AC: 2 slices of 16 t ----
    f32x4 s[2];
#pragma unroll
    for (int sl = 0; sl < 2; ++sl) {
      const __bf16* kp = kvb + ((size_t)(tb + ts * 32 + sl * 16 + li) * 4 + b) * 1024 + n * 64;
      f32x4 c = {0.f, 0.f, 0.f, 0.f};
      c = MFMA16(*(const bhalf8*)(kp + lq * 8), qu0, c);
      c = MFMA16(*(const bhalf8*)(kp + 32 + lq * 8), qu1, c);
      s[sl] = c;
    }
    // ---- scores (wave-private; compiler inserts lgkm wait for bdw) ----
    float sc[2][4];
    float tmax = -1e30f;
#pragma unroll
    for (int sl = 0; sl < 2; ++sl) {
#pragma unroll
      for (int r = 0; r < 4; ++r) {
        const int tloc = ts * 32 + sl * 16 + lq * 4 + r;
        const int t = tb + tloc;
        float v = -1e30f;
        if (t <= 1536 + i) {
          const int tk = t >> 9;
          const float gk = tk == 0 ? g0 : (tk == 1 ? g1 : (tk == 2 ? g2 : g3));
          v = s[sl][r] * gk + bdww[(sl * 16 + lq * 4 + r + 15 - li) * 18 + li];
        }
        sc[sl][r] = v;
        tmax = fmaxf(tmax, v);
      }
    }
    tmax = fmaxf(tmax, __shfl_xor(tmax, 16));
    tmax = fmaxf(tmax, __shfl_xor(tmax, 32));
    const float mnew = fmaxf(m_run, tmax);
    const float scl = __expf(m_run - mnew);
    float psum = 0.f;
    bhalf4 pk[2];
#pragma unroll
    for (int sl = 0; sl < 2; ++sl) {
#pragma unroll
      for (int r = 0; r < 4; ++r) {
        const float p = __expf(sc[sl][r] - mnew);
        psum += p;
        pk[sl][r] = (__bf16)p;
      }
    }
    psum += __shfl_xor(psum, 16);
    psum += __shfl_xor(psum, 32);
    l_run = l_run * scl + psum;
    m_run = mnew;
    // ---- ms + pb + pw ----
    if (l < 16)
      ms[((size_t)(plane << 6) + (tile << 2) + ts) * 512 + i] = mnew;
#pragma unroll
    for (int sl = 0; sl < 2; ++sl) {
      *(bhalf4*)(pb + ((size_t)plane * 512 + i) * 2048 + tb + ts * 32 + sl * 16 + lq * 4) = pk[sl];
      *(bhalf4*)(pww + li * 36 + sl * 16 + lq * 4) = pk[sl];
    }
    // ---- PV: one K=32 mfma per 16-d block (wave-private pw) ----
    const bhalf8 pfrag = *(const bhalf8*)(pww + li * 36 + lq * 8);
#pragma unroll
    for (int dsub = 0; dsub < 4; ++dsub) {
      oacc[dsub] *= scl;
      const __bf16* vp = vbase + (size_t)(dsub * 16 + li) * 2048 + tb + ts * 32 + lq * 8;
      oacc[dsub] = MFMA16(*(const bhalf8*)vp, pfrag, oacc[dsub]);
    }
  }

  // ---- end-of-block merge across the 4 waves per i-subtile ----
  __syncthreads();   // all waves done with bdw/pw before obuf overlay
  if (l < 16) { mlw[w][li][0] = m_run; mlw[w][li][1] = l_run; }
#pragma unroll
  for (int dsub = 0; dsub < 4; ++dsub)
    *(f32x4*)&obuf[(size_t)(w * 16 + li) * 68 + dsub * 16 + lq * 4] = oacc[dsub];
  __syncthreads();
  {
    const int iloc = tid >> 4, dq = tid & 15;
    const int it2 = iloc >> 4, lii = iloc & 15;
    float mk[4], lk[4];
#pragma unroll
    for (int k = 0; k < 4; ++k) {
      mk[k] = mlw[it2 + 2 * k][lii][0];
      lk[k] = mlw[it2 + 2 * k][lii][1];
    }
    const float mf = fmaxf(fmaxf(mk[0], mk[1]), fmaxf(mk[2], mk[3]));
    f32x4 o = {0.f, 0.f, 0.f, 0.f};
    float lf = 0.f;
#pragma unroll
    for (int k = 0; k < 4; ++k) {
      const float e = __expf(mk[k] - mf);
      lf += lk[k] * e;
      f32x4 ov = *(const f32x4*)&obuf[(size_t)((it2 + 2 * k) * 16 + lii) * 68 + dq * 4];
      o += ov * e;
    }
    const float inv = 1.f / lf;
    bhalf4 ov;
#pragma unroll
    for (int r = 0; r < 4; ++r) ov[r] = (__bf16)(o[r] * inv);
    *(bhalf4*)(vecb + ((size_t)(i0 + iloc) * 4 + b) * 512 + n * 64 + dq * 4) = ov;
    if (dq == 0) {
      float* mp = ml + ((size_t)plane * 512 + i0 + iloc) * 2;
      mp[0] = mf; mp[1] = lf;
    }
  }
}

// ---------------------------------------------------------------------------
// am_final: am[i,t] = (1/32) sum_p pb[p][i][t] * exp(ms[p][t32][i]-m_fin)/l_fin
// ms now per-32t-slice. Unwritten (fully masked) tiles excluded via weight 0.
// ---------------------------------------------------------------------------
__global__ __launch_bounds__(256) void am_final(
    const __bf16* __restrict__ pb, const float* __restrict__ ms,
    const float* __restrict__ ml, float* __restrict__ am)
{
  const int i = blockIdx.x;
  const int tid = threadIdx.x;
  const int t0 = tid << 3;
  const int t32 = t0 >> 5;
  const bool valid = (t0 >> 7) <= ((1536 + (i | 31)) >> 7);
  f32x4 a0 = {0.f, 0.f, 0.f, 0.f}, a1 = {0.f, 0.f, 0.f, 0.f};
#pragma unroll 4
  for (int p = 0; p < 32; ++p) {
    const float2 mlv = *(const float2*)(ml + ((size_t)p * 512 + i) * 2);
    float wgt = 0.f;
    if (valid)
      wgt = __expf(ms[((size_t)(p << 6) + t32) * 512 + i] - mlv.x) / mlv.y;
    bhalf8 v = *(const bhalf8*)(pb + ((size_t)p * 512 + i) * 2048 + t0);
    a0[0] += wgt * (float)v[0];
    a0[1] += wgt * (float)v[1];
    a0[2] += wgt * (float)v[2];
    a0[3] += wgt * (float)v[3];
    a1[0] += wgt * (float)v[4];
    a1[1] += wgt * (float)v[5];
    a1[2] += wgt * (float)v[6];
    a1[3] += wgt * (float)v[7];
  }
  const float sc = 1.f / 32.f;
  *(f32x4*)(am + (size_t)i * 2048 + t0)     = a0 * sc;
  *(f32x4*)(am + (size_t)i * 2048 + t0 + 4) = a1 * sc;
}

// ---------------------------------------------------------------------------
// Residual + LayerNorm
// ---------------------------------------------------------------------------
__global__ __launch_bounds__(256) void ln_f32(
    const float* __restrict__ x, const float* __restrict__ ao,
    const float* __restrict__ g, const float* __restrict__ bb,
    float* __restrict__ out)
{
  const int row = blockIdx.x;
  const int tid = threadIdx.x;
  const size_t base = (size_t)row * 512;
  const float y0 = x[base + tid] + ao[base + tid];
  const float y1 = x[base + 256 + tid] + ao[base + 256 + tid];
  float s  = y0 + y1;
  float ss = y0 * y0 + y1 * y1;
#pragma unroll
  for (int off = 32; off > 0; off >>= 1) {
    s  += __shfl_xor(s, off);
    ss += __shfl_xor(ss, off);
  }
  __shared__ float sred[4], ssred[4], stat[2];
  const int w = tid >> 6;
  if ((tid & 63) == 0) { sred[w] = s; ssred[w] = ss; }
  __syncthreads();
  if (tid == 0) {
    const float S  = sred[0] + sred[1] + sred[2] + sred[3];
    const float SS = ssred[0] + ssred[1] + ssred[2] + ssred[3];
    const float mu = S * (1.f / 512.f);
    const float var = SS * (1.f / 512.f) - mu * mu;
    stat[0] = mu;
    stat[1] = rsqrtf(var + 1e-5f);
  }
  __syncthreads();
  const float mu = stat[0], rs = stat[1];
  out[base + tid]       = (y0 - mu) * rs * g[tid] + bb[tid];
  out[base + 256 + tid] = (y1 - mu) * rs * g[256 + tid] + bb[256 + tid];
}

// ---------------------------------------------------------------------------
// Launch. ws layout (bf16 elem offsets):
//   vtb  @ 0           4,194,304
//   ms   @ 4,194,304   2,097,152  (1M f32; aof f32 overlays AFTER am_final)
//   kvb  @ 8,388,608   8,388,608
//   relb @ 16,777,216  4,194,304
//   qup  @ 20,971,520  1,048,576
//   qvp  @ 22,020,096  1,048,576
//   vecb @ 23,068,672  1,048,576
//   Wt   @ 24,117,248  1,310,720
//   ml   @ 25,427,968  65,536 (32K f32)
//   pb   @ 26,017,792  33,554,432   -> total ~119.1 MB
// ---------------------------------------------------------------------------
extern "C" void kernel_launch(void* const* d_in, const int* in_sizes, int n_in,
                              void* d_out, int out_size, void* d_ws, size_t ws_size,
                              hipStream_t stream)
{
  (void)in_sizes; (void)n_in; (void)out_size; (void)ws_size;
  const float* x      = (const float*)d_in[0];
  const float* memory = (const float*)d_in[1];
  const float* pos    = (const float*)d_in[2];
  const float* pbu    = (const float*)d_in[3];
  const float* pbv    = (const float*)d_in[4];
  const float* indice = (const float*)d_in[6];
  const float* W_q    = (const float*)d_in[7];
  const float* W_kv   = (const float*)d_in[8];
  const float* W_rel  = (const float*)d_in[9];
  const float* W_o    = (const float*)d_in[10];
  const float* ln_g   = (const float*)d_in[11];
  const float* ln_b   = (const float*)d_in[12];

  float* out = (float*)d_out;
  float* am  = out + 1048576;

  __bf16* ws    = (__bf16*)d_ws;
  __bf16* vtb   = ws;
  float*  msb   = (float*)(ws + 4194304);
  float*  aof   = msb;                      // overlay after am_final
  __bf16* kvb   = ws + 8388608;
  __bf16* relb  = ws + 16777216;
  __bf16* qup   = ws + 20971520;
  __bf16* qvp   = ws + 22020096;
  __bf16* vecb  = ws + 23068672;
  __bf16* wt    = ws + 24117248;
  __bf16* wqt   = wt;
  __bf16* wkvt  = wt + 512 * 512;
  __bf16* wrelt = wt + 1536 * 512;
  __bf16* wot   = wt + 2048 * 512;
  float*  ml    = (float*)(ws + 25427968);
  __bf16* pbuf  = ws + 26017792;

  transcast_all<<<dim3(8, 640), 256, 0, stream>>>(W_q, W_kv, W_rel, W_o, wt);

  gemm_bf16<2, 1><<<dim3(16, 4), 256, 0, stream>>>(x, x, 2048, wqt, (void*)qup,
                                                   2048, 512, 512, pbu, pbv, qup, qvp);
  gemm_bf16<0, 1><<<dim3(64, 8), 256, 0, stream>>>(memory, x, 6144, wkvt, kvb,
                                                   8192, 1024, 512,
                                                   nullptr, nullptr, nullptr, nullptr);
  gemm_bf16<0, 1><<<dim3(64, 4), 256, 0, stream>>>(pos, pos, 8192, wrelt, relb,
                                                   8192, 512, 512,
                                                   nullptr, nullptr, nullptr, nullptr);

  vtrans<<<dim3(32, 32), 256, 0, stream>>>(kvb, vtb);

  attn_v5<<<512, 512, 0, stream>>>(qup, qvp, kvb, relb, vtb, indice,
                                   vecb, ml, pbuf, msb);

  am_final<<<512, 256, 0, stream>>>(pbuf, msb, ml, am);

  gemm_bf16<1, 0><<<dim3(16, 4), 256, 0, stream>>>(vecb, vecb, 2048, wot, aof,
                                                   2048, 512, 512,
                                                   nullptr, nullptr, nullptr, nullptr);
  ln_f32<<<2048, 256, 0, stream>>>(x, aof, ln_g, ln_b, out);
}